// Round 9
// baseline (1534.699 us; speedup 1.0000x reference)
//
#include <hip/hip_runtime.h>
#include <stdint.h>

#define N_USER 50000
#define N_ITEM 50000
#define N_EDGE 600000
#define D 128

// ---- count in-degree per dst node ----
__global__ void k_cnt(const int* __restrict__ dst, int* __restrict__ c) {
  int e = blockIdx.x * blockDim.x + threadIdx.x;
  if (e >= N_EDGE) return;
  atomicAdd(&c[dst[e]], 1);
}

// ---- projection: Wh[m][n] = sum_k feat[m][k] * W[k][n] + b[n]  (all f32) ----
__global__ void k_proj(const float* __restrict__ feat, const float* __restrict__ W,
                       const float* __restrict__ b, float* __restrict__ Wh) {
  int gid = blockIdx.x * blockDim.x + threadIdx.x;   // [0, 50000*128)
  int m = gid >> 7, n = gid & 127;
  float acc = b[n];
  const float* fr = feat + (size_t)m * D;
#pragma unroll 8
  for (int k = 0; k < D; ++k) acc += fr[k] * W[k * D + n];
  Wh[gid] = acc;
}

// ---- per-edge scatter of Wh[src]/cnt[dst] directly into the f32 output plane ----
// block = 256 threads = 2 edges x 128 feature elements
__global__ void k_scatter(const float* __restrict__ Wh, const int* __restrict__ src,
                          const int* __restrict__ dst, const int* __restrict__ c,
                          float* __restrict__ P) {
  int e = blockIdx.x * 2 + (threadIdx.x >> 7);
  int k = threadIdx.x & 127;
  if (e >= N_EDGE) return;
  int s = src[e], d = dst[e];
  float inv = 1.0f / (float)c[d];                    // c[d] >= 1: this edge exists
  atomicAdd(&P[(size_t)d * D + k], Wh[(size_t)s * D + k] * inv);
}

extern "C" void kernel_launch(void* const* d_in, const int* in_sizes, int n_in,
                              void* d_out, int out_size, void* d_ws, size_t ws_size,
                              hipStream_t stream) {
  const float* fu  = (const float*)d_in[0];
  const float* fi  = (const float*)d_in[1];
  const float* Wuu = (const float*)d_in[2];
  const float* buu = (const float*)d_in[3];
  const float* Wub = (const float*)d_in[4];
  const float* bub = (const float*)d_in[5];
  const float* Wiu = (const float*)d_in[6];
  const float* biu = (const float*)d_in[7];
  const int* suu = (const int*)d_in[8];
  const int* duu = (const int*)d_in[9];
  const int* sub = (const int*)d_in[10];
  const int* dub = (const int*)d_in[11];
  const int* siu = (const int*)d_in[12];
  const int* diu = (const int*)d_in[13];

  // OUTPUT IS FLOAT32 (established round 8): [out_user 50000x128 | out_item 50000x128]
  float* out      = (float*)d_out;
  float* out_user = out;
  float* out_item = out + (size_t)N_USER * D;

  // workspace: c[150016 ints] | Wh f32[6.4M]  => ~26.2 MB (< 39 MB verified available)
  int*   c  = (int*)d_ws;                  // c_uu +0, c_ub +50000, c_iu +100000
  float* Wh = (float*)(c + 150016);

  const int EB = (N_EDGE + 255) / 256;
  const int SB = N_EDGE / 2;               // scatter: 2 edges/block
  const int PB = (N_USER * D) / 256;       // projection

  // zero output (harness poisons with 0xAA before every timed call) and counts
  hipMemsetAsync(out, 0, (size_t)2 * N_USER * D * sizeof(float), stream);
  hipMemsetAsync(c, 0, 150016 * sizeof(int), stream);
  k_cnt<<<EB, 256, 0, stream>>>(duu, c + 0);
  k_cnt<<<EB, 256, 0, stream>>>(dub, c + 50000);
  k_cnt<<<EB, 256, 0, stream>>>(diu, c + 100000);

  // ---- out_user = mean_uu(Wh_uu) + mean_iu(Wh_iu) ----
  k_proj<<<PB, 256, 0, stream>>>(fu, Wuu, buu, Wh);            // Wh_uu (bias inside)
  k_scatter<<<SB, 256, 0, stream>>>(Wh, suu, duu, c + 0, out_user);
  k_proj<<<PB, 256, 0, stream>>>(fi, Wiu, biu, Wh);            // Wh_iu (stream-ordered reuse)
  k_scatter<<<SB, 256, 0, stream>>>(Wh, siu, diu, c + 100000, out_user);

  // ---- out_item = mean_ub(Wh_ub) ----
  k_proj<<<PB, 256, 0, stream>>>(fu, Wub, bub, Wh);            // Wh_ub
  k_scatter<<<SB, 256, 0, stream>>>(Wh, sub, dub, c + 50000, out_item);
}

// Round 10
// 544.783 us; speedup vs baseline: 2.8171x; 2.8171x over previous
//
#include <hip/hip_runtime.h>
#include <stdint.h>
#include <string.h>

#define N_USER 50000
#define N_ITEM 50000
#define N_EDGE 600000
#define D 128
#define NTOT 150000      // 3 * 50000 destination slots (uu | ub | iu)
#define ETOT 1800000

typedef unsigned short u16;
typedef unsigned int   u32;
typedef __attribute__((ext_vector_type(8))) short short8;   // 8 bf16 (MFMA A/B frag)
typedef __attribute__((ext_vector_type(4))) float floatx4;  // MFMA C/D frag

static __device__ __forceinline__ u16 f2b(float f) {        // f32 -> bf16 RNE
  u32 x; memcpy(&x, &f, 4);
  u32 r = x + 0x7fffu + ((x >> 16) & 1u);
  return (u16)(r >> 16);
}

// ---- transpose + f32->bf16 the three 128x128 weights: WT[p][n*128+k] = bf16(W_p[k*128+n]) ----
__global__ void k_transpose(const float* __restrict__ W0, const float* __restrict__ W1,
                            const float* __restrict__ W2, u16* __restrict__ WT) {
  const float* W = (blockIdx.x == 0) ? W0 : ((blockIdx.x == 1) ? W1 : W2);
  u16* T = WT + blockIdx.x * D * D;
  for (int idx = threadIdx.x; idx < D * D; idx += blockDim.x) {
    int n = idx >> 7, k = idx & 127;
    T[idx] = f2b(W[k * D + n]);
  }
}

// ---- CSR build: count -> scan (LDS Hillis-Steele) -> fill ----
__global__ void k_count(const int* __restrict__ duu, const int* __restrict__ dub,
                        const int* __restrict__ diu, int* __restrict__ cnt) {
  int e = blockIdx.x * blockDim.x + threadIdx.x;
  if (e >= ETOT) return;
  int t = e / N_EDGE;
  int i = e - t * N_EDGE;
  int d = (t == 0) ? duu[i] : ((t == 1) ? dub[i] : diu[i]);
  atomicAdd(&cnt[t * N_USER + d], 1);
}

__global__ void k_scan1(const int* __restrict__ cnt, int* __restrict__ off, int* __restrict__ bsum) {
  __shared__ int buf[1024];
  int tid = threadIdx.x;
  int i = blockIdx.x * 1024 + tid;
  int v = (i < NTOT) ? cnt[i] : 0;     // virtual zero tail -> off[NTOT] = total
  buf[tid] = v;
  __syncthreads();
  for (int s = 1; s < 1024; s <<= 1) {
    int t = (tid >= s) ? buf[tid - s] : 0;
    __syncthreads();
    buf[tid] += t;
    __syncthreads();
  }
  if (i <= NTOT) off[i] = buf[tid] - v;            // exclusive
  if (tid == 0) bsum[blockIdx.x] = buf[1023];
}

__global__ void k_scan2(int* __restrict__ bsum, int nb) {
  __shared__ int buf[256];
  int t = threadIdx.x;
  int v = (t < nb) ? bsum[t] : 0;
  buf[t] = v;
  __syncthreads();
  for (int s = 1; s < 256; s <<= 1) {
    int y = (t >= s) ? buf[t - s] : 0;
    __syncthreads();
    buf[t] += y;
    __syncthreads();
  }
  if (t < nb) bsum[t] = buf[t] - v;                // exclusive block offsets
}

__global__ void k_fix(int* __restrict__ off, int* __restrict__ woff, const int* __restrict__ bsum) {
  int i = blockIdx.x * blockDim.x + threadIdx.x;
  if (i > NTOT) return;
  int v = off[i] + bsum[i >> 10];
  off[i] = v;
  woff[i] = v;
}

__global__ void k_fill(const int* __restrict__ suu, const int* __restrict__ duu,
                       const int* __restrict__ sub, const int* __restrict__ dub,
                       const int* __restrict__ siu, const int* __restrict__ diu,
                       int* __restrict__ woff, int* __restrict__ ssrc) {
  int e = blockIdx.x * blockDim.x + threadIdx.x;
  if (e >= ETOT) return;
  int t = e / N_EDGE;
  int i = e - t * N_EDGE;
  int d, s;
  if (t == 0)      { d = duu[i]; s = suu[i]; }
  else if (t == 1) { d = dub[i]; s = sub[i]; }
  else             { d = diu[i]; s = siu[i]; }
  int pos = atomicAdd(&woff[t * N_USER + d], 1);
  ssrc[pos] = s;
}

// ---- gather-mean of raw f32 features per (type,dst), one wave per slot ----
// mean_uu -> out rows [0,50000); mean_ub -> out rows [50000,100000); mean_iu -> ws (f32).
__global__ void __launch_bounds__(256) k_mean(const float* __restrict__ fu, const float* __restrict__ fi,
                                              const int* __restrict__ off, const int* __restrict__ ssrc,
                                              float* __restrict__ out, float* __restrict__ mean_iu) {
  int slot = blockIdx.x * 4 + (threadIdx.x >> 6);
  int lane = threadIdx.x & 63;
  if (slot >= NTOT) return;
  int t = slot / N_USER;            // 0:uu 1:ub 2:iu
  int d = slot - t * N_USER;
  const float* feat = (t == 2) ? fi : fu;   // uu,ub gather user feats; iu gathers item feats
  int s = off[slot], e = off[slot + 1];
  float a0 = 0.f, a1 = 0.f;
  int i = s;
  for (; i + 4 <= e; i += 4) {      // 4 row-loads in flight
    int s0 = ssrc[i], s1 = ssrc[i + 1], s2 = ssrc[i + 2], s3 = ssrc[i + 3];
    float2 v0 = ((const float2*)(feat + (size_t)s0 * D))[lane];
    float2 v1 = ((const float2*)(feat + (size_t)s1 * D))[lane];
    float2 v2 = ((const float2*)(feat + (size_t)s2 * D))[lane];
    float2 v3 = ((const float2*)(feat + (size_t)s3 * D))[lane];
    a0 += v0.x + v1.x + v2.x + v3.x;
    a1 += v0.y + v1.y + v2.y + v3.y;
  }
  for (; i < e; ++i) {
    float2 v = ((const float2*)(feat + (size_t)ssrc[i] * D))[lane];
    a0 += v.x; a1 += v.y;
  }
  int n = e - s;
  float inv = (n > 0) ? 1.0f / (float)n : 0.f;
  float* dst = (t == 0) ? (out + (size_t)d * D)
             : (t == 1) ? (out + (size_t)(N_USER + d) * D)
                        : (mean_iu + (size_t)d * D);
  ((float2*)dst)[lane] = make_float2(a0 * inv, a1 * inv);
}

// ---- final GEMM, in-place on d_out (f32), self-calibrating MFMA C/D layout ----
// y=0 (users): out_u = mean_uu@W_uu + mask(n_uu)*b_uu + mean_iu@W_iu + mask(n_iu)*b_iu
// y=1 (items): out_i = mean_ub@W_ub + mask(n_ub)*b_ub
__global__ void __launch_bounds__(256) k_out(float* out, const float* __restrict__ mean_iu,
                                             const u16* __restrict__ WT,
                                             const float* __restrict__ buu, const float* __restrict__ bub,
                                             const float* __restrict__ biu, const int* __restrict__ off) {
  int users = (blockIdx.y == 0);
  int tid = threadIdx.x;
  int w = tid >> 6, lane = tid & 63, quad = lane >> 4, l16 = lane & 15;
  int row_base = blockIdx.x * 64;
  int r0 = row_base + w * 16 + l16;
  int rA = r0 < N_USER ? r0 : N_USER - 1;   // clamp tail (stores guarded)

  // runtime C/D layout probe: D = I_16 * B, B[k][n] = k*16+n (bf16-exact <=255)
  short8 apb, bpb;
#pragma unroll
  for (int j = 0; j < 8; j++) {
    int k = quad * 8 + j;
    apb[j] = (short)((k == l16) ? 0x3F80 : 0);                  // bf16(1.0) on diagonal
    bpb[j] = (short)((k < 16) ? f2b((float)(k * 16 + l16)) : 0);
  }
  floatx4 pz = (floatx4){0.f, 0.f, 0.f, 0.f};
  floatx4 pr = __builtin_amdgcn_mfma_f32_16x16x32_bf16(apb, bpb, pz, 0, 0, 0);
  int rowm[4], colm[4];
#pragma unroll
  for (int i = 0; i < 4; i++) { int v = (int)pr[i]; rowm[i] = v >> 4; colm[i] = v & 15; }

  floatx4 acc[8];
#pragma unroll
  for (int i = 0; i < 8; i++) acc[i] = (floatx4){0.f, 0.f, 0.f, 0.f};

  // pass 1: users -> mean_uu (out rows 0..); items -> mean_ub (out rows 50000..)
  {
    const float* A0 = users ? out : (out + (size_t)N_USER * D);
    const u16* W0 = users ? WT : (WT + D * D);
    const float* abase = A0 + (size_t)rA * D + quad * 8;
#pragma unroll
    for (int kk = 0; kk < 4; ++kk) {
      const float4* ap = (const float4*)(abase + kk * 32);
      float4 v0 = ap[0], v1 = ap[1];
      short8 af;
      af[0] = (short)f2b(v0.x); af[1] = (short)f2b(v0.y);
      af[2] = (short)f2b(v0.z); af[3] = (short)f2b(v0.w);
      af[4] = (short)f2b(v1.x); af[5] = (short)f2b(v1.y);
      af[6] = (short)f2b(v1.z); af[7] = (short)f2b(v1.w);
      const short8* bptr = (const short8*)(W0 + l16 * D + kk * 32 + quad * 8);
#pragma unroll
      for (int nt = 0; nt < 8; ++nt)
        acc[nt] = __builtin_amdgcn_mfma_f32_16x16x32_bf16(af, bptr[nt * 256], acc[nt], 0, 0, 0);
    }
  }
  // pass 2 (users only): += mean_iu @ plane2
  if (users) {
    const float* abase = mean_iu + (size_t)rA * D + quad * 8;
    const u16* W2 = WT + 2 * D * D;
#pragma unroll
    for (int kk = 0; kk < 4; ++kk) {
      const float4* ap = (const float4*)(abase + kk * 32);
      float4 v0 = ap[0], v1 = ap[1];
      short8 af;
      af[0] = (short)f2b(v0.x); af[1] = (short)f2b(v0.y);
      af[2] = (short)f2b(v0.z); af[3] = (short)f2b(v0.w);
      af[4] = (short)f2b(v1.x); af[5] = (short)f2b(v1.y);
      af[6] = (short)f2b(v1.z); af[7] = (short)f2b(v1.w);
      const short8* bptr = (const short8*)(W2 + l16 * D + kk * 32 + quad * 8);
#pragma unroll
      for (int nt = 0; nt < 8; ++nt)
        acc[nt] = __builtin_amdgcn_mfma_f32_16x16x32_bf16(af, bptr[nt * 256], acc[nt], 0, 0, 0);
    }
  }

  // stage 64x128 f32 in LDS with the PROBED (row,col) mapping, then masked bias + f32 store.
  // In-place safety: every wave's A-loads complete before its LDS writes (dataflow),
  // and __syncthreads orders all LDS writes before any global store.
  __shared__ float lds[64 * 132];
#pragma unroll
  for (int nt = 0; nt < 8; ++nt)
#pragma unroll
    for (int r = 0; r < 4; ++r)
      lds[(w * 16 + rowm[r]) * 132 + nt * 16 + colm[r]] = acc[nt][r];
  __syncthreads();

#pragma unroll
  for (int i = 0; i < 4; i++) {
    int linear = tid + i * 256;
    int row = linear >> 4;
    int cg  = (linear & 15) * 8;
    int grow = row_base + row;
    if (grow < N_USER) {
      float res[8];
      if (users) {
        int n0 = off[grow + 1] - off[grow];
        int n2 = off[2 * N_USER + grow + 1] - off[2 * N_USER + grow];
#pragma unroll
        for (int j = 0; j < 8; j++) {
          float b = (n0 > 0 ? buu[cg + j] : 0.f) + (n2 > 0 ? biu[cg + j] : 0.f);
          res[j] = lds[row * 132 + cg + j] + b;
        }
        float4* dst = (float4*)(out + (size_t)grow * D + cg);
        dst[0] = make_float4(res[0], res[1], res[2], res[3]);
        dst[1] = make_float4(res[4], res[5], res[6], res[7]);
      } else {
        int n1 = off[N_USER + grow + 1] - off[N_USER + grow];
#pragma unroll
        for (int j = 0; j < 8; j++) {
          float b = (n1 > 0 ? bub[cg + j] : 0.f);
          res[j] = lds[row * 132 + cg + j] + b;
        }
        float4* dst = (float4*)(out + (size_t)(N_USER + grow) * D + cg);
        dst[0] = make_float4(res[0], res[1], res[2], res[3]);
        dst[1] = make_float4(res[4], res[5], res[6], res[7]);
      }
    }
  }
}

extern "C" void kernel_launch(void* const* d_in, const int* in_sizes, int n_in,
                              void* d_out, int out_size, void* d_ws, size_t ws_size,
                              hipStream_t stream) {
  const float* fu  = (const float*)d_in[0];
  const float* fi  = (const float*)d_in[1];
  const float* Wuu = (const float*)d_in[2];
  const float* buu = (const float*)d_in[3];
  const float* Wub = (const float*)d_in[4];
  const float* bub = (const float*)d_in[5];
  const float* Wiu = (const float*)d_in[6];
  const float* biu = (const float*)d_in[7];
  const int* suu = (const int*)d_in[8];
  const int* duu = (const int*)d_in[9];
  const int* sub = (const int*)d_in[10];
  const int* dub = (const int*)d_in[11];
  const int* siu = (const int*)d_in[12];
  const int* diu = (const int*)d_in[13];
  float* out = (float*)d_out;   // f32: [out_user 50000x128 | out_item 50000x128]

  // workspace (34.7 MB <= 39 MB verified): ints then WT bf16 then mean_iu f32
  int* wsi  = (int*)d_ws;
  int* off  = wsi;                 // [150001]
  int* woff = wsi + 150016;        // [150001]
  int* cnt  = wsi + 300032;        // [150000]
  int* bsum = wsi + 450048;        // [256]
  int* ssrc = wsi + 450304;        // [1800000]
  u16*   WT      = (u16*)(wsi + 2250304);   // 3*128*128 bf16 (96 KB), 16B-aligned
  float* mean_iu = (float*)(wsi + 2274880); // 50000*128 f32 (25.6 MB)

  hipMemsetAsync(cnt, 0, NTOT * sizeof(int), stream);
  k_transpose<<<3, 256, 0, stream>>>(Wuu, Wub, Wiu, WT);
  k_count<<<(ETOT + 255) / 256, 256, 0, stream>>>(duu, dub, diu, cnt);
  k_scan1<<<147, 1024, 0, stream>>>(cnt, off, bsum);
  k_scan2<<<1, 256, 0, stream>>>(bsum, 147);
  k_fix<<<(NTOT + 1 + 255) / 256, 256, 0, stream>>>(off, woff, bsum);
  k_fill<<<(ETOT + 255) / 256, 256, 0, stream>>>(suu, duu, sub, dub, siu, diu, woff, ssrc);
  k_mean<<<37500, 256, 0, stream>>>(fu, fi, off, ssrc, out, mean_iu);
  k_out<<<dim3(782, 2), 256, 0, stream>>>(out, mean_iu, WT, buu, bub, biu, off);
}

// Round 11
// 482.871 us; speedup vs baseline: 3.1783x; 1.1282x over previous
//
#include <hip/hip_runtime.h>
#include <stdint.h>
#include <string.h>

#define N_USER 50000
#define N_ITEM 50000
#define N_EDGE 600000
#define D 128
#define NTOT 150000      // 3 * 50000 destination slots (uu | ub | iu)
#define ETOT 1800000

typedef unsigned short u16;
typedef unsigned int   u32;
typedef __attribute__((ext_vector_type(8))) short short8;   // 8 bf16 (MFMA A/B frag)
typedef __attribute__((ext_vector_type(4))) float floatx4;  // MFMA C/D frag

static __device__ __forceinline__ u16 f2b(float f) {        // f32 -> bf16 RNE
  u32 x; memcpy(&x, &f, 4);
  u32 r = x + 0x7fffu + ((x >> 16) & 1u);
  return (u16)(r >> 16);
}
static __device__ __forceinline__ float blo2f(u32 v) {      // low 16 bits as bf16
  u32 x = v << 16; float f; memcpy(&f, &x, 4); return f;
}
static __device__ __forceinline__ float bhi2f(u32 v) {      // high 16 bits as bf16
  u32 x = v & 0xffff0000u; float f; memcpy(&f, &x, 4); return f;
}

// ---- transpose + f32->bf16 the three 128x128 weights: WT[p][n*128+k] = bf16(W_p[k*128+n]) ----
__global__ void k_transpose(const float* __restrict__ W0, const float* __restrict__ W1,
                            const float* __restrict__ W2, u16* __restrict__ WT) {
  const float* W = (blockIdx.x == 0) ? W0 : ((blockIdx.x == 1) ? W1 : W2);
  u16* T = WT + blockIdx.x * D * D;
  for (int idx = threadIdx.x; idx < D * D; idx += blockDim.x) {
    int n = idx >> 7, k = idx & 127;
    T[idx] = f2b(W[k * D + n]);
  }
}

// ---- bf16 copy of user features (uu+ub gather source): fb_u = bf16(fu) ----
__global__ void k_cvt(const float* __restrict__ fu, u16* __restrict__ fb) {
  int gid = blockIdx.x * blockDim.x + threadIdx.x;   // over float4 groups: 1.6M
  const float4 v = ((const float4*)fu)[gid];
  union { u16 u[4]; uint2 d; } pk;
  pk.u[0] = f2b(v.x); pk.u[1] = f2b(v.y); pk.u[2] = f2b(v.z); pk.u[3] = f2b(v.w);
  ((uint2*)fb)[gid] = pk.d;
}

// ---- CSR build: count -> scan (LDS Hillis-Steele) -> fill ----
__global__ void k_count(const int* __restrict__ duu, const int* __restrict__ dub,
                        const int* __restrict__ diu, int* __restrict__ cnt) {
  int e = blockIdx.x * blockDim.x + threadIdx.x;
  if (e >= ETOT) return;
  int t = e / N_EDGE;
  int i = e - t * N_EDGE;
  int d = (t == 0) ? duu[i] : ((t == 1) ? dub[i] : diu[i]);
  atomicAdd(&cnt[t * N_USER + d], 1);
}

__global__ void k_scan1(const int* __restrict__ cnt, int* __restrict__ off, int* __restrict__ bsum) {
  __shared__ int buf[1024];
  int tid = threadIdx.x;
  int i = blockIdx.x * 1024 + tid;
  int v = (i < NTOT) ? cnt[i] : 0;     // virtual zero tail -> off[NTOT] = total
  buf[tid] = v;
  __syncthreads();
  for (int s = 1; s < 1024; s <<= 1) {
    int t = (tid >= s) ? buf[tid - s] : 0;
    __syncthreads();
    buf[tid] += t;
    __syncthreads();
  }
  if (i <= NTOT) off[i] = buf[tid] - v;            // exclusive
  if (tid == 0) bsum[blockIdx.x] = buf[1023];
}

__global__ void k_scan2(int* __restrict__ bsum, int nb) {
  __shared__ int buf[256];
  int t = threadIdx.x;
  int v = (t < nb) ? bsum[t] : 0;
  buf[t] = v;
  __syncthreads();
  for (int s = 1; s < 256; s <<= 1) {
    int y = (t >= s) ? buf[t - s] : 0;
    __syncthreads();
    buf[t] += y;
    __syncthreads();
  }
  if (t < nb) bsum[t] = buf[t] - v;                // exclusive block offsets
}

__global__ void k_fix(int* __restrict__ off, int* __restrict__ woff, const int* __restrict__ bsum) {
  int i = blockIdx.x * blockDim.x + threadIdx.x;
  if (i > NTOT) return;
  int v = off[i] + bsum[i >> 10];
  off[i] = v;
  woff[i] = v;
}

__global__ void k_fill(const int* __restrict__ suu, const int* __restrict__ duu,
                       const int* __restrict__ sub, const int* __restrict__ dub,
                       const int* __restrict__ siu, const int* __restrict__ diu,
                       int* __restrict__ woff, u16* __restrict__ ssrc) {
  int e = blockIdx.x * blockDim.x + threadIdx.x;
  if (e >= ETOT) return;
  int t = e / N_EDGE;
  int i = e - t * N_EDGE;
  int d, s;
  if (t == 0)      { d = duu[i]; s = suu[i]; }
  else if (t == 1) { d = dub[i]; s = sub[i]; }
  else             { d = diu[i]; s = siu[i]; }
  int pos = atomicAdd(&woff[t * N_USER + d], 1);
  ssrc[pos] = (u16)s;                              // src < 50000 < 65536
}

// ---- gather-mean per (type,dst), one wave per slot; f32 accumulate ----
// t=0 (uu): gather bf16 fb_u -> mean f32 to out rows [0,50000)
// t=1 (ub): gather bf16 fb_u -> mean f32 to out rows [50000,100000)
// t=2 (iu): gather f32  fi   -> mean bf16 to ws (feeds k_out pass 2 directly)
__global__ void __launch_bounds__(256) k_mean(const u16* __restrict__ fb_u, const float* __restrict__ fi,
                                              const int* __restrict__ off, const u16* __restrict__ ssrc,
                                              float* __restrict__ out, u16* __restrict__ mean_iu) {
  int slot = blockIdx.x * 4 + (threadIdx.x >> 6);
  int lane = threadIdx.x & 63;
  if (slot >= NTOT) return;
  int t = slot / N_USER;
  int d = slot - t * N_USER;
  int s = off[slot], e = off[slot + 1];
  float a0 = 0.f, a1 = 0.f;
  if (t < 2) {                       // bf16 gather: 256 B/row, lane reads u32 (cols 2l, 2l+1)
    int i = s;
    for (; i + 4 <= e; i += 4) {
      int s0 = ssrc[i], s1 = ssrc[i + 1], s2 = ssrc[i + 2], s3 = ssrc[i + 3];
      u32 v0 = ((const u32*)(fb_u + (size_t)s0 * D))[lane];
      u32 v1 = ((const u32*)(fb_u + (size_t)s1 * D))[lane];
      u32 v2 = ((const u32*)(fb_u + (size_t)s2 * D))[lane];
      u32 v3 = ((const u32*)(fb_u + (size_t)s3 * D))[lane];
      a0 += blo2f(v0) + blo2f(v1) + blo2f(v2) + blo2f(v3);
      a1 += bhi2f(v0) + bhi2f(v1) + bhi2f(v2) + bhi2f(v3);
    }
    for (; i < e; ++i) {
      u32 v = ((const u32*)(fb_u + (size_t)ssrc[i] * D))[lane];
      a0 += blo2f(v); a1 += bhi2f(v);
    }
  } else {                           // f32 gather: 512 B/row, lane reads float2
    int i = s;
    for (; i + 4 <= e; i += 4) {
      int s0 = ssrc[i], s1 = ssrc[i + 1], s2 = ssrc[i + 2], s3 = ssrc[i + 3];
      float2 v0 = ((const float2*)(fi + (size_t)s0 * D))[lane];
      float2 v1 = ((const float2*)(fi + (size_t)s1 * D))[lane];
      float2 v2 = ((const float2*)(fi + (size_t)s2 * D))[lane];
      float2 v3 = ((const float2*)(fi + (size_t)s3 * D))[lane];
      a0 += v0.x + v1.x + v2.x + v3.x;
      a1 += v0.y + v1.y + v2.y + v3.y;
    }
    for (; i < e; ++i) {
      float2 v = ((const float2*)(fi + (size_t)ssrc[i] * D))[lane];
      a0 += v.x; a1 += v.y;
    }
  }
  int n = e - s;
  float inv = (n > 0) ? 1.0f / (float)n : 0.f;
  a0 *= inv; a1 *= inv;
  if (t < 2) {
    float* dst = out + (size_t)(t * N_USER + d) * D;
    ((float2*)dst)[lane] = make_float2(a0, a1);
  } else {
    u32 pk = (u32)f2b(a0) | ((u32)f2b(a1) << 16);
    ((u32*)(mean_iu + (size_t)d * D))[lane] = pk;
  }
}

// ---- final GEMM, in-place on d_out (f32), self-calibrating MFMA C/D layout ----
__global__ void __launch_bounds__(256) k_out(float* out, const u16* __restrict__ mean_iu,
                                             const u16* __restrict__ WT,
                                             const float* __restrict__ buu, const float* __restrict__ bub,
                                             const float* __restrict__ biu, const int* __restrict__ off) {
  int users = (blockIdx.y == 0);
  int tid = threadIdx.x;
  int w = tid >> 6, lane = tid & 63, quad = lane >> 4, l16 = lane & 15;
  int row_base = blockIdx.x * 64;
  int r0 = row_base + w * 16 + l16;
  int rA = r0 < N_USER ? r0 : N_USER - 1;   // clamp tail (stores guarded)

  // runtime C/D layout probe: D = I_16 * B, B[k][n] = k*16+n (bf16-exact <=255)
  short8 apb, bpb;
#pragma unroll
  for (int j = 0; j < 8; j++) {
    int k = quad * 8 + j;
    apb[j] = (short)((k == l16) ? 0x3F80 : 0);
    bpb[j] = (short)((k < 16) ? f2b((float)(k * 16 + l16)) : 0);
  }
  floatx4 pz = (floatx4){0.f, 0.f, 0.f, 0.f};
  floatx4 pr = __builtin_amdgcn_mfma_f32_16x16x32_bf16(apb, bpb, pz, 0, 0, 0);
  int rowm[4], colm[4];
#pragma unroll
  for (int i = 0; i < 4; i++) { int v = (int)pr[i]; rowm[i] = v >> 4; colm[i] = v & 15; }

  floatx4 acc[8];
#pragma unroll
  for (int i = 0; i < 8; i++) acc[i] = (floatx4){0.f, 0.f, 0.f, 0.f};

  // pass 1: users -> mean_uu (out rows 0..); items -> mean_ub (out rows 50000..)
  {
    const float* A0 = users ? out : (out + (size_t)N_USER * D);
    const u16* W0 = users ? WT : (WT + D * D);
    const float* abase = A0 + (size_t)rA * D + quad * 8;
#pragma unroll
    for (int kk = 0; kk < 4; ++kk) {
      const float4* ap = (const float4*)(abase + kk * 32);
      float4 v0 = ap[0], v1 = ap[1];
      short8 af;
      af[0] = (short)f2b(v0.x); af[1] = (short)f2b(v0.y);
      af[2] = (short)f2b(v0.z); af[3] = (short)f2b(v0.w);
      af[4] = (short)f2b(v1.x); af[5] = (short)f2b(v1.y);
      af[6] = (short)f2b(v1.z); af[7] = (short)f2b(v1.w);
      const short8* bptr = (const short8*)(W0 + l16 * D + kk * 32 + quad * 8);
#pragma unroll
      for (int nt = 0; nt < 8; ++nt)
        acc[nt] = __builtin_amdgcn_mfma_f32_16x16x32_bf16(af, bptr[nt * 256], acc[nt], 0, 0, 0);
    }
  }
  // pass 2 (users only): += mean_iu (already bf16 -> direct frag loads) @ plane2
  if (users) {
    const short8* aptr = (const short8*)(mean_iu + (size_t)rA * D + quad * 8);
    const u16* W2 = WT + 2 * D * D;
#pragma unroll
    for (int kk = 0; kk < 4; ++kk) {
      short8 af = aptr[kk * 4];
      const short8* bptr = (const short8*)(W2 + l16 * D + kk * 32 + quad * 8);
#pragma unroll
      for (int nt = 0; nt < 8; ++nt)
        acc[nt] = __builtin_amdgcn_mfma_f32_16x16x32_bf16(af, bptr[nt * 256], acc[nt], 0, 0, 0);
    }
  }

  // stage 64x128 f32 in LDS with the PROBED (row,col) mapping, then masked bias + f32 store
  __shared__ float lds[64 * 132];
#pragma unroll
  for (int nt = 0; nt < 8; ++nt)
#pragma unroll
    for (int r = 0; r < 4; ++r)
      lds[(w * 16 + rowm[r]) * 132 + nt * 16 + colm[r]] = acc[nt][r];
  __syncthreads();

#pragma unroll
  for (int i = 0; i < 4; i++) {
    int linear = tid + i * 256;
    int row = linear >> 4;
    int cg  = (linear & 15) * 8;
    int grow = row_base + row;
    if (grow < N_USER) {
      float res[8];
      if (users) {
        int n0 = off[grow + 1] - off[grow];
        int n2 = off[2 * N_USER + grow + 1] - off[2 * N_USER + grow];
#pragma unroll
        for (int j = 0; j < 8; j++) {
          float b = (n0 > 0 ? buu[cg + j] : 0.f) + (n2 > 0 ? biu[cg + j] : 0.f);
          res[j] = lds[row * 132 + cg + j] + b;
        }
        float4* dst = (float4*)(out + (size_t)grow * D + cg);
        dst[0] = make_float4(res[0], res[1], res[2], res[3]);
        dst[1] = make_float4(res[4], res[5], res[6], res[7]);
      } else {
        int n1 = off[N_USER + grow + 1] - off[N_USER + grow];
#pragma unroll
        for (int j = 0; j < 8; j++) {
          float b = (n1 > 0 ? bub[cg + j] : 0.f);
          res[j] = lds[row * 132 + cg + j] + b;
        }
        float4* dst = (float4*)(out + (size_t)(N_USER + grow) * D + cg);
        dst[0] = make_float4(res[0], res[1], res[2], res[3]);
        dst[1] = make_float4(res[4], res[5], res[6], res[7]);
      }
    }
  }
}

extern "C" void kernel_launch(void* const* d_in, const int* in_sizes, int n_in,
                              void* d_out, int out_size, void* d_ws, size_t ws_size,
                              hipStream_t stream) {
  const float* fu  = (const float*)d_in[0];
  const float* fi  = (const float*)d_in[1];
  const float* Wuu = (const float*)d_in[2];
  const float* buu = (const float*)d_in[3];
  const float* Wub = (const float*)d_in[4];
  const float* bub = (const float*)d_in[5];
  const float* Wiu = (const float*)d_in[6];
  const float* biu = (const float*)d_in[7];
  const int* suu = (const int*)d_in[8];
  const int* duu = (const int*)d_in[9];
  const int* sub = (const int*)d_in[10];
  const int* dub = (const int*)d_in[11];
  const int* siu = (const int*)d_in[12];
  const int* diu = (const int*)d_in[13];
  float* out = (float*)d_out;   // f32: [out_user 50000x128 | out_item 50000x128]

  // workspace (31.1 MB <= 39 MB verified)
  int* wsi  = (int*)d_ws;
  int* off  = wsi;                          // [150001]
  int* woff = wsi + 150016;                 // [150001]
  int* cnt  = wsi + 300032;                 // [150000]
  int* bsum = wsi + 450048;                 // [256]
  u16* ssrc = (u16*)(wsi + 450304);         // [1800000] u16 (3.6 MB)
  u16* WT   = (u16*)(wsi + 1350304);        // 3*128*128 bf16 (96 KB), 16B-aligned
  u16* fb_u = (u16*)(wsi + 1374880);        // 50000*128 bf16 (12.8 MB), 16B-aligned
  u16* mean_iu = (u16*)(wsi + 4574880);     // 50000*128 bf16 (12.8 MB), 16B-aligned

  hipMemsetAsync(cnt, 0, NTOT * sizeof(int), stream);
  k_transpose<<<3, 256, 0, stream>>>(Wuu, Wub, Wiu, WT);
  k_cvt<<<(N_USER * D / 4) / 256, 256, 0, stream>>>(fu, fb_u);
  k_count<<<(ETOT + 255) / 256, 256, 0, stream>>>(duu, dub, diu, cnt);
  k_scan1<<<147, 1024, 0, stream>>>(cnt, off, bsum);
  k_scan2<<<1, 256, 0, stream>>>(bsum, 147);
  k_fix<<<(NTOT + 1 + 255) / 256, 256, 0, stream>>>(off, woff, bsum);
  k_fill<<<(ETOT + 255) / 256, 256, 0, stream>>>(suu, duu, sub, dub, siu, diu, woff, ssrc);
  k_mean<<<37500, 256, 0, stream>>>(fb_u, fi, off, ssrc, out, mean_iu);
  k_out<<<dim3(782, 2), 256, 0, stream>>>(out, mean_iu, WT, buu, bub, biu, off);
}

// Round 12
// 376.061 us; speedup vs baseline: 4.0810x; 1.2840x over previous
//
#include <hip/hip_runtime.h>
#include <stdint.h>
#include <string.h>

#define N_USER 50000
#define N_ITEM 50000
#define N_EDGE 600000
#define D 128
#define NTOT 150000      // 3 * 50000 destination slots (uu | ub | iu)
#define ETOT 1800000
#define NB 147           // buckets = ceil(NTOT / SPAN)
#define BSH 10
#define SPAN 1024        // slots per bucket
#define CHUNK 4096       // edges per block in bucket kernels (16/thread)

typedef unsigned short u16;
typedef unsigned int   u32;
typedef __attribute__((ext_vector_type(8))) short short8;   // 8 bf16 (MFMA A/B frag)
typedef __attribute__((ext_vector_type(4))) float floatx4;  // MFMA C/D frag

static __device__ __forceinline__ u16 f2b(float f) {        // f32 -> bf16 RNE
  u32 x; memcpy(&x, &f, 4);
  u32 r = x + 0x7fffu + ((x >> 16) & 1u);
  return (u16)(r >> 16);
}
static __device__ __forceinline__ float blo2f(u32 v) {
  u32 x = v << 16; float f; memcpy(&f, &x, 4); return f;
}
static __device__ __forceinline__ float bhi2f(u32 v) {
  u32 x = v & 0xffff0000u; float f; memcpy(&f, &x, 4); return f;
}

// ---- prep: blocks 0-2 transpose+bf16 the weights; blocks 3+ convert fu to bf16 ----
__global__ void k_prep(const float* __restrict__ W0, const float* __restrict__ W1,
                       const float* __restrict__ W2, u16* __restrict__ WT,
                       const float* __restrict__ fu, u16* __restrict__ fb_u) {
  int bid = blockIdx.x;
  if (bid < 3) {
    const float* W = (bid == 0) ? W0 : ((bid == 1) ? W1 : W2);
    u16* T = WT + bid * D * D;
    for (int idx = threadIdx.x; idx < D * D; idx += blockDim.x) {
      int n = idx >> 7, k = idx & 127;
      T[idx] = f2b(W[k * D + n]);
    }
  } else {
    int gid = (bid - 3) * 256 + threadIdx.x;    // float4 groups: 1.6M
    float4 v = ((const float4*)fu)[gid];
    union { u16 u[4]; uint2 d; } pk;
    pk.u[0] = f2b(v.x); pk.u[1] = f2b(v.y); pk.u[2] = f2b(v.z); pk.u[3] = f2b(v.w);
    ((uint2*)fb_u)[gid] = pk.d;
  }
}

// ---- bucket histogram: LDS-staged, 147 coarse global atomics per block ----
__global__ void __launch_bounds__(256) k_bhist(const int* __restrict__ duu, const int* __restrict__ dub,
                                               const int* __restrict__ diu, int* __restrict__ bhist) {
  __shared__ int h[NB];
  for (int i = threadIdx.x; i < NB; i += 256) h[i] = 0;
  __syncthreads();
  int base = blockIdx.x * CHUNK;
  for (int j = threadIdx.x; j < CHUNK; j += 256) {
    int e = base + j;
    if (e < ETOT) {
      int t = e / N_EDGE, i = e - t * N_EDGE;
      int d = (t == 0) ? duu[i] : ((t == 1) ? dub[i] : diu[i]);
      atomicAdd(&h[(t * N_USER + d) >> BSH], 1);
    }
  }
  __syncthreads();
  for (int i = threadIdx.x; i < NB; i += 256) if (h[i]) atomicAdd(&bhist[i], h[i]);
}

// ---- exclusive scan of 147 bucket totals (1 block) ----
__global__ void k_bscan(const int* __restrict__ bhist, int* __restrict__ boff) {
  __shared__ int buf[256];
  int t = threadIdx.x;
  int v = (t < NB) ? bhist[t] : 0;
  buf[t] = v; __syncthreads();
  for (int s = 1; s < 256; s <<= 1) {
    int y = (t >= s) ? buf[t - s] : 0;
    __syncthreads(); buf[t] += y; __syncthreads();
  }
  if (t <= NB) boff[t] = (t == 0) ? 0 : buf[t - 1];
}

// ---- place edges into bucket-grouped ebuf: payload = src | (slot&1023)<<16 ----
__global__ void __launch_bounds__(256) k_bplace(
    const int* __restrict__ suu, const int* __restrict__ duu,
    const int* __restrict__ sub, const int* __restrict__ dub,
    const int* __restrict__ siu, const int* __restrict__ diu,
    const int* __restrict__ boff, int* __restrict__ cursor, u32* __restrict__ ebuf) {
  __shared__ int h[NB];
  for (int i = threadIdx.x; i < NB; i += 256) h[i] = 0;
  __syncthreads();
  int base = blockIdx.x * CHUNK;
  u32 pay[16], br[16];
#pragma unroll
  for (int k = 0; k < 16; ++k) {
    int e = base + k * 256 + threadIdx.x;
    br[k] = 0xFFFFFFFFu;
    if (e < ETOT) {
      int t = e / N_EDGE, i = e - t * N_EDGE;
      int d, s;
      if (t == 0)      { d = duu[i]; s = suu[i]; }
      else if (t == 1) { d = dub[i]; s = sub[i]; }
      else             { d = diu[i]; s = siu[i]; }
      int slot = t * N_USER + d;
      int bu = slot >> BSH;
      int rank = atomicAdd(&h[bu], 1);
      pay[k] = (u32)s | ((u32)(slot & (SPAN - 1)) << 16);
      br[k]  = (u32)bu | ((u32)rank << 8);       // bu<=146 fits 8 bits; rank<4096
    }
  }
  __syncthreads();
  for (int i = threadIdx.x; i < NB; i += 256)
    h[i] = boff[i] + atomicAdd(&cursor[i], h[i]);    // block's base within bucket region
  __syncthreads();
#pragma unroll
  for (int k = 0; k < 16; ++k) {
    if (br[k] != 0xFFFFFFFFu) {
      int bu = br[k] & 0xFF, rank = (int)(br[k] >> 8);
      ebuf[h[bu] + rank] = pay[k];
    }
  }
}

// ---- per-bucket CSR finalize: off[] (coalesced) + ssrc[] (L2-local scatter) ----
__global__ void __launch_bounds__(256) k_csr(const int* __restrict__ boff, const u32* __restrict__ ebuf,
                                             int* __restrict__ off, u16* __restrict__ ssrc) {
  __shared__ int sc[SPAN];
  __shared__ int so[SPAN];
  __shared__ int part[256];
  int b = blockIdx.x;
  int ebase = boff[b], ecnt = boff[b + 1] - ebase;
  int sbase = b << BSH;
  int nslots = (NTOT - sbase < SPAN) ? (NTOT - sbase) : SPAN;
  for (int i = threadIdx.x; i < SPAN; i += 256) sc[i] = 0;
  __syncthreads();
  for (int j = threadIdx.x; j < ecnt; j += 256)
    atomicAdd(&sc[ebuf[ebase + j] >> 16], 1);
  __syncthreads();
  int t = threadIdx.x;
  int s0 = sc[4*t], s1 = sc[4*t+1], s2 = sc[4*t+2], s3 = sc[4*t+3];
  int tsum = s0 + s1 + s2 + s3;
  part[t] = tsum; __syncthreads();
  for (int s = 1; s < 256; s <<= 1) {
    int y = (t >= s) ? part[t - s] : 0;
    __syncthreads(); part[t] += y; __syncthreads();
  }
  int pbase = part[t] - tsum;
  so[4*t]   = pbase;
  so[4*t+1] = pbase + s0;
  so[4*t+2] = pbase + s0 + s1;
  so[4*t+3] = pbase + s0 + s1 + s2;
  __syncthreads();
  for (int i = threadIdx.x; i < nslots; i += 256)
    off[sbase + i] = ebase + so[i];
  if (b == 0 && threadIdx.x == 0) off[NTOT] = ETOT;
  for (int i = threadIdx.x; i < SPAN; i += 256) sc[i] = so[i];   // cursors
  __syncthreads();
  for (int j = threadIdx.x; j < ecnt; j += 256) {
    u32 p = ebuf[ebase + j];
    int pos = atomicAdd(&sc[p >> 16], 1);
    ssrc[ebase + pos] = (u16)(p & 0xFFFFu);
  }
}

// ---- gather-mean per (type,dst), one wave per slot (unchanged from r11) ----
__global__ void __launch_bounds__(256) k_mean(const u16* __restrict__ fb_u, const float* __restrict__ fi,
                                              const int* __restrict__ off, const u16* __restrict__ ssrc,
                                              float* __restrict__ out, u16* __restrict__ mean_iu) {
  int slot = blockIdx.x * 4 + (threadIdx.x >> 6);
  int lane = threadIdx.x & 63;
  if (slot >= NTOT) return;
  int t = slot / N_USER;
  int d = slot - t * N_USER;
  int s = off[slot], e = off[slot + 1];
  float a0 = 0.f, a1 = 0.f;
  if (t < 2) {
    int i = s;
    for (; i + 4 <= e; i += 4) {
      int s0 = ssrc[i], s1 = ssrc[i + 1], s2 = ssrc[i + 2], s3 = ssrc[i + 3];
      u32 v0 = ((const u32*)(fb_u + (size_t)s0 * D))[lane];
      u32 v1 = ((const u32*)(fb_u + (size_t)s1 * D))[lane];
      u32 v2 = ((const u32*)(fb_u + (size_t)s2 * D))[lane];
      u32 v3 = ((const u32*)(fb_u + (size_t)s3 * D))[lane];
      a0 += blo2f(v0) + blo2f(v1) + blo2f(v2) + blo2f(v3);
      a1 += bhi2f(v0) + bhi2f(v1) + bhi2f(v2) + bhi2f(v3);
    }
    for (; i < e; ++i) {
      u32 v = ((const u32*)(fb_u + (size_t)ssrc[i] * D))[lane];
      a0 += blo2f(v); a1 += bhi2f(v);
    }
  } else {
    int i = s;
    for (; i + 4 <= e; i += 4) {
      int s0 = ssrc[i], s1 = ssrc[i + 1], s2 = ssrc[i + 2], s3 = ssrc[i + 3];
      float2 v0 = ((const float2*)(fi + (size_t)s0 * D))[lane];
      float2 v1 = ((const float2*)(fi + (size_t)s1 * D))[lane];
      float2 v2 = ((const float2*)(fi + (size_t)s2 * D))[lane];
      float2 v3 = ((const float2*)(fi + (size_t)s3 * D))[lane];
      a0 += v0.x + v1.x + v2.x + v3.x;
      a1 += v0.y + v1.y + v2.y + v3.y;
    }
    for (; i < e; ++i) {
      float2 v = ((const float2*)(fi + (size_t)ssrc[i] * D))[lane];
      a0 += v.x; a1 += v.y;
    }
  }
  int n = e - s;
  float inv = (n > 0) ? 1.0f / (float)n : 0.f;
  a0 *= inv; a1 *= inv;
  if (t < 2) {
    float* dst = out + (size_t)(t * N_USER + d) * D;
    ((float2*)dst)[lane] = make_float2(a0, a1);
  } else {
    u32 pk = (u32)f2b(a0) | ((u32)f2b(a1) << 16);
    ((u32*)(mean_iu + (size_t)d * D))[lane] = pk;
  }
}

// ---- final GEMM, in-place on d_out (f32), self-calibrating MFMA C/D layout ----
__global__ void __launch_bounds__(256) k_out(float* out, const u16* __restrict__ mean_iu,
                                             const u16* __restrict__ WT,
                                             const float* __restrict__ buu, const float* __restrict__ bub,
                                             const float* __restrict__ biu, const int* __restrict__ off) {
  int users = (blockIdx.y == 0);
  int tid = threadIdx.x;
  int w = tid >> 6, lane = tid & 63, quad = lane >> 4, l16 = lane & 15;
  int row_base = blockIdx.x * 64;
  int r0 = row_base + w * 16 + l16;
  int rA = r0 < N_USER ? r0 : N_USER - 1;

  short8 apb, bpb;
#pragma unroll
  for (int j = 0; j < 8; j++) {
    int k = quad * 8 + j;
    apb[j] = (short)((k == l16) ? 0x3F80 : 0);
    bpb[j] = (short)((k < 16) ? f2b((float)(k * 16 + l16)) : 0);
  }
  floatx4 pz = (floatx4){0.f, 0.f, 0.f, 0.f};
  floatx4 pr = __builtin_amdgcn_mfma_f32_16x16x32_bf16(apb, bpb, pz, 0, 0, 0);
  int rowm[4], colm[4];
#pragma unroll
  for (int i = 0; i < 4; i++) { int v = (int)pr[i]; rowm[i] = v >> 4; colm[i] = v & 15; }

  floatx4 acc[8];
#pragma unroll
  for (int i = 0; i < 8; i++) acc[i] = (floatx4){0.f, 0.f, 0.f, 0.f};

  {
    const float* A0 = users ? out : (out + (size_t)N_USER * D);
    const u16* W0 = users ? WT : (WT + D * D);
    const float* abase = A0 + (size_t)rA * D + quad * 8;
#pragma unroll
    for (int kk = 0; kk < 4; ++kk) {
      const float4* ap = (const float4*)(abase + kk * 32);
      float4 v0 = ap[0], v1 = ap[1];
      short8 af;
      af[0] = (short)f2b(v0.x); af[1] = (short)f2b(v0.y);
      af[2] = (short)f2b(v0.z); af[3] = (short)f2b(v0.w);
      af[4] = (short)f2b(v1.x); af[5] = (short)f2b(v1.y);
      af[6] = (short)f2b(v1.z); af[7] = (short)f2b(v1.w);
      const short8* bptr = (const short8*)(W0 + l16 * D + kk * 32 + quad * 8);
#pragma unroll
      for (int nt = 0; nt < 8; ++nt)
        acc[nt] = __builtin_amdgcn_mfma_f32_16x16x32_bf16(af, bptr[nt * 256], acc[nt], 0, 0, 0);
    }
  }
  if (users) {
    const short8* aptr = (const short8*)(mean_iu + (size_t)rA * D + quad * 8);
    const u16* W2 = WT + 2 * D * D;
#pragma unroll
    for (int kk = 0; kk < 4; ++kk) {
      short8 af = aptr[kk * 4];
      const short8* bptr = (const short8*)(W2 + l16 * D + kk * 32 + quad * 8);
#pragma unroll
      for (int nt = 0; nt < 8; ++nt)
        acc[nt] = __builtin_amdgcn_mfma_f32_16x16x32_bf16(af, bptr[nt * 256], acc[nt], 0, 0, 0);
    }
  }

  __shared__ float lds[64 * 132];
#pragma unroll
  for (int nt = 0; nt < 8; ++nt)
#pragma unroll
    for (int r = 0; r < 4; ++r)
      lds[(w * 16 + rowm[r]) * 132 + nt * 16 + colm[r]] = acc[nt][r];
  __syncthreads();

#pragma unroll
  for (int i = 0; i < 4; i++) {
    int linear = tid + i * 256;
    int row = linear >> 4;
    int cg  = (linear & 15) * 8;
    int grow = row_base + row;
    if (grow < N_USER) {
      float res[8];
      if (users) {
        int n0 = off[grow + 1] - off[grow];
        int n2 = off[2 * N_USER + grow + 1] - off[2 * N_USER + grow];
#pragma unroll
        for (int j = 0; j < 8; j++) {
          float b = (n0 > 0 ? buu[cg + j] : 0.f) + (n2 > 0 ? biu[cg + j] : 0.f);
          res[j] = lds[row * 132 + cg + j] + b;
        }
        float4* dst = (float4*)(out + (size_t)grow * D + cg);
        dst[0] = make_float4(res[0], res[1], res[2], res[3]);
        dst[1] = make_float4(res[4], res[5], res[6], res[7]);
      } else {
        int n1 = off[N_USER + grow + 1] - off[N_USER + grow];
#pragma unroll
        for (int j = 0; j < 8; j++) {
          float b = (n1 > 0 ? bub[cg + j] : 0.f);
          res[j] = lds[row * 132 + cg + j] + b;
        }
        float4* dst = (float4*)(out + (size_t)(N_USER + grow) * D + cg);
        dst[0] = make_float4(res[0], res[1], res[2], res[3]);
        dst[1] = make_float4(res[4], res[5], res[6], res[7]);
      }
    }
  }
}

extern "C" void kernel_launch(void* const* d_in, const int* in_sizes, int n_in,
                              void* d_out, int out_size, void* d_ws, size_t ws_size,
                              hipStream_t stream) {
  const float* fu  = (const float*)d_in[0];
  const float* fi  = (const float*)d_in[1];
  const float* Wuu = (const float*)d_in[2];
  const float* buu = (const float*)d_in[3];
  const float* Wub = (const float*)d_in[4];
  const float* bub = (const float*)d_in[5];
  const float* Wiu = (const float*)d_in[6];
  const float* biu = (const float*)d_in[7];
  const int* suu = (const int*)d_in[8];
  const int* duu = (const int*)d_in[9];
  const int* sub = (const int*)d_in[10];
  const int* dub = (const int*)d_in[11];
  const int* siu = (const int*)d_in[12];
  const int* diu = (const int*)d_in[13];
  float* out = (float*)d_out;   // f32: [out_user 50000x128 | out_item 50000x128]

  // workspace layout (37.1 MB <= 39 MB verified)
  int* wsi    = (int*)d_ws;
  int* off    = wsi;                        // [150001]
  int* bhist  = wsi + 150016;               // [147]
  int* cursor = wsi + 150208;               // [147]
  int* boff   = wsi + 150400;               // [148]
  u32* ebuf   = (u32*)(wsi + 150592);       // [1800000] (7.2 MB)
  u16* ssrc   = (u16*)(wsi + 1950592);      // [1800000] u16 (3.6 MB)
  u16* WT     = (u16*)(wsi + 2850592);      // 3*128*128 bf16, 16B-aligned
  u16* fb_u   = (u16*)(wsi + 2875168);      // 50000*128 bf16 (12.8 MB)
  u16* mean_iu= (u16*)(wsi + 6075168);      // 50000*128 bf16 (12.8 MB)

  const int NBLK = (ETOT + CHUNK - 1) / CHUNK;   // 440

  hipMemsetAsync(bhist, 0, 384 * sizeof(int), stream);   // bhist + cursor
  k_prep<<<3 + (N_USER * D / 4) / 256, 256, 0, stream>>>(Wuu, Wub, Wiu, WT, fu, fb_u);
  k_bhist<<<NBLK, 256, 0, stream>>>(duu, dub, diu, bhist);
  k_bscan<<<1, 256, 0, stream>>>(bhist, boff);
  k_bplace<<<NBLK, 256, 0, stream>>>(suu, duu, sub, dub, siu, diu, boff, cursor, ebuf);
  k_csr<<<NB, 256, 0, stream>>>(boff, ebuf, off, ssrc);
  k_mean<<<37500, 256, 0, stream>>>(fb_u, fi, off, ssrc, out, mean_iu);
  k_out<<<dim3(782, 2), 256, 0, stream>>>(out, mean_iu, WT, buu, bub, biu, off);
}